// Round 12
// baseline (2527.808 us; speedup 1.0000x reference)
//
#include <hip/hip_runtime.h>

typedef __attribute__((ext_vector_type(8))) short bf16x8;
typedef __attribute__((ext_vector_type(8))) unsigned short u16x8;
typedef __attribute__((ext_vector_type(4))) unsigned short u16x4;
typedef __attribute__((ext_vector_type(4))) float f32x4;
typedef __attribute__((ext_vector_type(2))) unsigned int u32x2;

#define NB 32
#define NT 512
#define ND 256
#define NE 1024
#define NH 1024
#define LSTM_SMEM (131072 + 18432)   // W frags (hi+lo) + reduce buffer [16][32][9] f32

__device__ __forceinline__ float bf2f(unsigned short u){
  union { unsigned int i; float f; } w; w.i = ((unsigned int)u) << 16; return w.f;
}
__device__ __forceinline__ unsigned short f2bf(float f){
  union { float f; unsigned int i; } w; w.f = f;
  unsigned int r = (w.i >> 16) & 1u;
  return (unsigned short)((w.i + 0x7fffu + r) >> 16);
}

// ---- cache-bypass (coherence-point) memory ops ----
__device__ __forceinline__ bf16x8 bypass_load_b128(const unsigned short* p){
  bf16x8 r;
  asm volatile("global_load_dwordx4 %0, %1, off sc0 sc1" : "=v"(r) : "v"(p) : "memory");
  return r;  // caller must s_waitcnt before use
}
__device__ __forceinline__ int bypass_load_i32(const int* p){
  int r;
  asm volatile("global_load_dword %0, %1, off sc0 sc1\n\ts_waitcnt vmcnt(0)"
               : "=v"(r) : "v"(p) : "memory");
  return r;
}
__device__ __forceinline__ void bypass_store_b64(unsigned short* p, u32x2 v){
  asm volatile("global_store_dwordx2 %0, %1, off sc0 sc1" :: "v"(p), "v"(v) : "memory");
}
__device__ __forceinline__ void bypass_store_i32(int* p, int v){
  asm volatile("global_store_dword %0, %1, off sc0 sc1" :: "v"(p), "v"(v) : "memory");
}

// ---- global_load_lds width=16 (m97 pattern) ----
__device__ __forceinline__ void gload_lds16(const void* g, void* l){
  __builtin_amdgcn_global_load_lds(
      (const __attribute__((address_space(1))) void*)g,
      (__attribute__((address_space(3))) void*)l, 16, 0, 0);
}

// ---- bijective XCD swizzle (m204) ----
__device__ __forceinline__ int xcd_swizzle(int orig, int nwg){
  int q = nwg >> 3, r = nwg & 7;
  int xcd = orig & 7, idx = orig >> 3;
  return (xcd < r ? xcd*(q+1) : r*(q+1) + (xcd-r)*q) + idx;
}

// ---------------- one-shot prep: weight conversion + state init ----------------
__global__ void mega_prep(const float* __restrict__ W1, const float* __restrict__ W2,
                          const float* __restrict__ Wih,
                          const float* __restrict__ Wa, const float* __restrict__ Wc,
                          const float* __restrict__ ba, const float* __restrict__ bc,
                          const float* __restrict__ b_ih, const float* __restrict__ b_hh,
                          const float* __restrict__ hxs, const float* __restrict__ cxs,
                          unsigned short* __restrict__ W1_b, unsigned short* __restrict__ W2_b,
                          unsigned short* __restrict__ Wih_b, unsigned short* __restrict__ Whead_b,
                          float* __restrict__ bias_heads, float* __restrict__ bias_xg,
                          unsigned short* __restrict__ h16, float* __restrict__ c_buf,
                          int* __restrict__ flags)
{
  long i0 = (long)blockIdx.x*256 + threadIdx.x;
  long stride = (long)gridDim.x*256;
  for (long i=i0; i<(long)NE*ND;   i+=stride) W1_b[i]  = f2bf(W1[i]);
  for (long i=i0; i<(long)NE*NE;   i+=stride) W2_b[i]  = f2bf(W2[i]);
  for (long i=i0; i<(long)4*NH*NE; i+=stride) Wih_b[i] = f2bf(Wih[i]);
  for (long i=i0; i<128*1024; i+=stride){
    int n = (int)(i>>10), k = (int)(i&1023);
    Whead_b[i] = f2bf(n<64 ? Wa[i] : (n==64 ? Wc[k] : 0.f));
  }
  for (long i=i0; i<4096; i+=stride) bias_xg[i] = b_ih[i] + b_hh[i];
  for (long i=i0; i<65;   i+=stride) bias_heads[i] = (i<64) ? ba[i] : bc[0];
  for (long i=i0; i<NB*NH; i+=stride){ h16[i] = f2bf(hxs[i]); c_buf[i] = cxs[i]; }
  for (long i=i0; i<8192; i+=stride) flags[i] = 0;
}

__global__ void f2b_obs_chunk(const float* __restrict__ obs, unsigned short* __restrict__ dst,
                              int lgTc, int t0){
  const int Tc = 1 << lgTc;
  const long n = (long)NB * Tc * ND;
  long i = (long)blockIdx.x*blockDim.x + threadIdx.x;
  long stride = (long)gridDim.x*blockDim.x;
  for (; i < n; i += stride){
    long lr = i >> 8;
    int col = (int)(i & 255);
    long gr = (lr >> lgTc)*NT + t0 + (lr & (Tc-1));
    dst[i] = f2bf(obs[gr*ND + col]);
  }
}

__global__ void sentinel_kernel(float* __restrict__ out){ out[0] = 1.0e6f; }

// ---------------- bf16 MFMA GEMM: 128x128, dbuf LDS, 2-phase prefetch, XCD swizzle ----------------
// REMAP=1: output row m (local, chunk) -> (m>>lgR)*NT + tR + (m & (1<<lgR)-1)  (full-T layout)
#define GEMM_COMPUTE(P) { \
  bf16x8 af[4], bfr[4]; \
  _Pragma("unroll") for (int f=0; f<4; f++){ \
    af[f]  = *(const bf16x8*)&As[P][(wm*64 + f*16 + fr)*32 + kf]; \
    bfr[f] = *(const bf16x8*)&Bs[P][(wn*64 + f*16 + fr)*32 + kf]; } \
  _Pragma("unroll") for (int i=0;i<4;i++) \
    _Pragma("unroll") for (int j=0;j<4;j++) \
      acc[i][j] = __builtin_amdgcn_mfma_f32_16x16x32_bf16(af[i], bfr[j], acc[i][j], 0, 0, 0); }

template<int SILU, int HEADS, int REMAP>
__global__ __launch_bounds__(256)
void gemm_bt(const unsigned short* __restrict__ A, const unsigned short* __restrict__ Bw,
             const float* __restrict__ bias, unsigned short* __restrict__ C,
             float* __restrict__ oLogits, float* __restrict__ oValues,
             int K, int N, int Nreal, int lgR, int tR)
{
  __shared__ __align__(16) unsigned short As[2][128*32];
  __shared__ __align__(16) unsigned short Bs[2][128*32];
  const int tid = threadIdx.x;
  const int lane = tid & 63;
  const int w = tid >> 6;
  const int wm = w >> 1, wn = w & 1;
  const int nwg = gridDim.x * gridDim.y;
  const int wgid = xcd_swizzle(blockIdx.y * gridDim.x + blockIdx.x, nwg);
  const int m0 = (wgid % gridDim.x) * 128;
  const int n0 = (wgid / gridDim.x) * 128;
  f32x4 acc[4][4];
#pragma unroll
  for (int i=0;i<4;i++)
#pragma unroll
    for (int j=0;j<4;j++){ f32x4 z = {0.f,0.f,0.f,0.f}; acc[i][j] = z; }
  const int fr = lane & 15;
  const int kf = (lane >> 4) * 8;
  const int r0 = tid >> 2, s0 = tid & 3;
  const unsigned short* gA0 = A  + (size_t)(m0+r0)*K    + s0*8;
  const unsigned short* gA1 = A  + (size_t)(m0+r0+64)*K + s0*8;
  const unsigned short* gB0 = Bw + (size_t)(n0+r0)*K    + s0*8;
  const unsigned short* gB1 = Bw + (size_t)(n0+r0+64)*K + s0*8;

  auto stage = [&](int p, int k0){
    char* a = (char*)&As[p][0] + w*1024;
    char* b = (char*)&Bs[p][0] + w*1024;
    gload_lds16(gA0 + k0, a);
    gload_lds16(gA1 + k0, a + 4096);
    gload_lds16(gB0 + k0, b);
    gload_lds16(gB1 + k0, b + 4096);
  };

  stage(0, 0);
  asm volatile("s_waitcnt vmcnt(0)" ::: "memory");
  __syncthreads();
  int cur = 0;
  for (int k0 = 32; k0 < K; k0 += 32){
    stage(cur ^ 1, k0);
    GEMM_COMPUTE(cur);
    asm volatile("s_waitcnt vmcnt(0)" ::: "memory");
    __syncthreads();
    cur ^= 1;
  }
  GEMM_COMPUTE(cur);

  const int mb = (lane >> 4) * 4;
  const int nb = lane & 15;
#pragma unroll
  for (int i=0;i<4;i++)
#pragma unroll
    for (int j=0;j<4;j++)
#pragma unroll
      for (int r=0;r<4;r++){
        int m = m0 + wm*64 + i*16 + mb + r;
        int n = n0 + wn*64 + j*16 + nb;
        if (HEADS && n >= Nreal) continue;
        float v = acc[i][j][r] + bias[n];
        if (SILU) v = v / (1.f + expf(-v));
        if (!HEADS) {
          size_t orow = (size_t)m;
          if (REMAP) orow = (size_t)(m >> lgR)*NT + tR + (m & ((1<<lgR)-1));
          C[orow*N + n] = f2bf(v);
        } else {
          if (n < 64) oLogits[(size_t)m*64 + n] = v;
          else if (n == 64) oValues[m] = v;
        }
      }
}

// ---------------- LSTM: persistent MFMA kernel, latency-pipelined xg ----------------
// 256 WGs x 512 thr. WG (bh=wg&1, ug=wg>>1): batches b0=bh*16..+16, units n0w=ug*8..+8.
// xg consumed one step LATE (xcur/xnext pipeline); xg loads issued after h-loads so the
// counted vmcnt(4) protects h while xg flies under the MFMA phase. Poll loop never has
// other vmem outstanding (all drained at publish), so its vmcnt(0) waits only the flag.
__global__ __launch_bounds__(512)
void lstm_mfma(const unsigned short* __restrict__ xg, const float* __restrict__ Whh,
               unsigned short* __restrict__ h16, float* __restrict__ c_buf,
               unsigned short* __restrict__ hist, float* __restrict__ dh, float* __restrict__ dc,
               int* __restrict__ flags, int t0, int t1, int Tc)
{
  extern __shared__ char smem[];
  unsigned short* Wf = (unsigned short*)smem;          // [term][kt 32][nt 2][lane 64] x 8 ushort
  float* red = (float*)(smem + 131072);                // [batch 16][row 32][wv 9] (pad 9)
  const int wg = blockIdx.x;
  const int bh = wg & 1, ug = wg >> 1;
  const int b0 = bh*16, n0w = ug*8;
  const int tid = threadIdx.x;
  const int lane = tid & 63;
  const int wv = tid >> 6;
  const int fr = lane & 15;
  const int q8 = (lane >> 4) * 8;

  // ---- one-time: stage W hi/lo fragments ----
  for (int s = tid; s < 8192; s += 512){
    int term = s >> 12, kt = (s >> 7) & 31, nt = (s >> 6) & 1, l = s & 63;
    int r = nt*16 + (l & 15);
    int g = r >> 3, uu2 = r & 7;
    const float* src = Whh + (size_t)(g*NH + n0w + uu2)*NH + kt*32 + (l>>4)*8;
    u16x8 o;
#pragma unroll
    for (int j=0;j<8;j++){
      float wv_ = src[j];
      unsigned short hi = f2bf(wv_);
      o[j] = (term==0) ? hi : f2bf(wv_ - bf2f(hi));
    }
    *(u16x8*)&Wf[(size_t)s*8] = o;
  }

  const int bl = wv*2 + (lane >> 3);   // batch-local 0..15 (lane<16)
  const int uu = lane & 7;             // unit 0..7
  float c_reg = 0.f, h_keep = 0.f;
  float xcur[4] = {0.f,0.f,0.f,0.f};
  if (lane < 16){
    c_reg = c_buf[(b0 + bl)*NH + n0w + uu];
    size_t xb = ((size_t)(b0+bl)*Tc + 0)*4096 + n0w + uu;   // tl=0 for first step
#pragma unroll
    for (int g=0; g<4; g++) xcur[g] = bf2f(xg[xb + (size_t)g*1024]);
  }
  __syncthreads();

  int pcur = t0 % 3;
  for (int t = t0; t < t1; t++){
    const int pnext = (pcur == 2) ? 0 : pcur + 1;
    const unsigned short* hb = h16 + (size_t)pcur  * (NB*NH);
    unsigned short* hb_next  = h16 + (size_t)pnext * (NB*NH);
    const int tl = t - t0;

    // ---- per-wave producer poll (nothing else in flight: publish drained all) ----
    {
      const int pw = ((wv*16 + fr)*2 + bh) * 32;
      while (true){
        int v = bypass_load_i32(&flags[pw]);
        v = min(v, __shfl_xor(v, 1));
        v = min(v, __shfl_xor(v, 2));
        v = min(v, __shfl_xor(v, 4));
        v = min(v, __shfl_xor(v, 8));
        if (v >= t) break;
        __builtin_amdgcn_s_sleep(1);
      }
    }

    // ---- h A-frag loads FIRST (the 4 oldest vmem ops of this step) ----
    bf16x8 a[4];
#pragma unroll
    for (int ks=0; ks<4; ks++)
      a[ks] = bypass_load_b128(hb + (size_t)(b0 + fr)*NH + (wv*4 + ks)*32 + q8);

    // ---- xg prefetch for NEXT step (flies under MFMA; consumed next iteration) ----
    unsigned short xnext[4] = {0,0,0,0};
    if (lane < 16){
      const int tn = (t+1 < t1) ? (tl+1) : tl;
      size_t xb = ((size_t)(b0+bl)*Tc + tn)*4096 + n0w + uu;
#pragma unroll
      for (int g=0; g<4; g++) xnext[g] = xg[xb + (size_t)g*1024];
    }

    // counted wait: drains the 4 h-loads (oldest), leaves xg prefetch in flight
    asm volatile("s_waitcnt vmcnt(4)" ::: "memory");
    __builtin_amdgcn_sched_barrier(0);

    f32x4 acc[2];
    { f32x4 z = {0.f,0.f,0.f,0.f}; acc[0] = z; acc[1] = z; }
#pragma unroll
    for (int ks=0; ks<4; ks++){
      int kt = wv*4 + ks;
#pragma unroll
      for (int nt=0; nt<2; nt++){
        bf16x8 bhi = *(const bf16x8*)&Wf[kt*1024 + nt*512 + lane*8];
        bf16x8 blo = *(const bf16x8*)&Wf[32768 + kt*1024 + nt*512 + lane*8];
        acc[nt] = __builtin_amdgcn_mfma_f32_16x16x32_bf16(a[ks], bhi, acc[nt], 0,0,0);
        acc[nt] = __builtin_amdgcn_mfma_f32_16x16x32_bf16(a[ks], blo, acc[nt], 0,0,0);
      }
    }

    // ---- cross-wave reduce ----
#pragma unroll
    for (int nt=0; nt<2; nt++)
#pragma unroll
      for (int r4=0; r4<4; r4++){
        int batch = (lane>>4)*4 + r4;
        red[batch*288 + (nt*16 + fr)*9 + wv] = acc[nt][r4];
      }
    __syncthreads();

    // ---- epilogue: gates from xcur (loaded LAST step -> guaranteed complete) ----
    unsigned short p0=0,p1=0,p2=0,p3=0;
    if (lane < 16){
      float gate[4];
#pragma unroll
      for (int g=0; g<4; g++){
        const float* rp = &red[bl*288 + (g*8 + uu)*9];
        float s = 0.f;
#pragma unroll
        for (int w8=0; w8<8; w8++) s += rp[w8];
        gate[g] = s + xcur[g];
      }
      float iv = 1.f/(1.f+expf(-gate[0]));
      float fv = 1.f/(1.f+expf(-gate[1]));
      float gv = tanhf(gate[2]);
      float ov = 1.f/(1.f+expf(-gate[3]));
      float c_new = fv*c_reg + iv*gv;
      float h_new = ov*tanhf(c_new);
      c_reg = c_new; h_keep = h_new;
      float h0 = __shfl(h_new, (lane & ~3) + 0);
      float h1 = __shfl(h_new, (lane & ~3) + 1);
      float h2 = __shfl(h_new, (lane & ~3) + 2);
      float h3 = __shfl(h_new, (lane & ~3) + 3);
      if ((lane & 3) == 0){
        p0 = f2bf(h0); p1 = f2bf(h1); p2 = f2bf(h2); p3 = f2bf(h3);
        u32x2 pk; pk[0] = (unsigned)p0 | ((unsigned)p1 << 16);
        pk[1] = (unsigned)p2 | ((unsigned)p3 << 16);
        bypass_store_b64(hb_next + (size_t)(b0+bl)*NH + n0w + uu, pk);
      }
    }
    // ---- publish: drain (h-store + residual xg prefetch ~0), then flag ----
    asm volatile("s_waitcnt vmcnt(0)" ::: "memory");
    __syncthreads();
    if (tid == 0) bypass_store_i32(&flags[wg*32], t+1);
    // hist store AFTER publish (off the critical path)
    if (lane < 16 && (lane & 3) == 0){
      u16x4 hp = { p0, p1, p2, p3 };
      *(u16x4*)&hist[((size_t)(b0+bl)*Tc + tl)*NH + n0w + uu] = hp;
    }
    // rotate pipeline (loads already drained; converts are free)
    if (lane < 16){
#pragma unroll
      for (int g=0; g<4; g++) xcur[g] = bf2f(xnext[g]);
    }
    pcur = pnext;
  }
  if (lane < 16){
    c_buf[(b0+bl)*NH + n0w + uu] = c_reg;
    if (t1 == NT){ dh[(b0+bl)*NH + n0w + uu] = h_keep; dc[(b0+bl)*NH + n0w + uu] = c_reg; }
  }
}

// ---------------- LayerNorm: wave-per-row, 4 rows/block ----------------
__global__ __launch_bounds__(256)
void ln_chunk(const unsigned short* __restrict__ X, const float* __restrict__ gam, const float* __restrict__ bet,
              unsigned short* __restrict__ Y, int lgTc, int t0)
{
  const int Tc = 1 << lgTc;
  const int row = blockIdx.x*4 + (threadIdx.x >> 6);
  const int lane = threadIdx.x & 63;
  const int bl = row >> lgTc, tl = row & (Tc-1);
  const long grow = (long)bl*NT + t0 + tl;
  u16x8 a0 = *(const u16x8*)&X[(size_t)row*NH + lane*16];
  u16x8 a1 = *(const u16x8*)&X[(size_t)row*NH + lane*16 + 8];
  float x[16];
  float s = 0.f;
#pragma unroll
  for (int j=0;j<8;j++){ x[j] = bf2f(a0[j]); x[8+j] = bf2f(a1[j]); }
#pragma unroll
  for (int j=0;j<16;j++) s += x[j];
  s += __shfl_xor(s,1); s += __shfl_xor(s,2); s += __shfl_xor(s,4);
  s += __shfl_xor(s,8); s += __shfl_xor(s,16); s += __shfl_xor(s,32);
  const float mean = s * (1.0f/NH);
  float q = 0.f;
#pragma unroll
  for (int j=0;j<16;j++){ float d = x[j]-mean; q += d*d; }
  q += __shfl_xor(q,1); q += __shfl_xor(q,2); q += __shfl_xor(q,4);
  q += __shfl_xor(q,8); q += __shfl_xor(q,16); q += __shfl_xor(q,32);
  const float rs = 1.f / sqrtf(q * (1.0f/NH) + 1e-5f);
  f32x4 g0 = *(const f32x4*)&gam[lane*16];
  f32x4 g1 = *(const f32x4*)&gam[lane*16+4];
  f32x4 g2 = *(const f32x4*)&gam[lane*16+8];
  f32x4 g3 = *(const f32x4*)&gam[lane*16+12];
  f32x4 b0 = *(const f32x4*)&bet[lane*16];
  f32x4 b1 = *(const f32x4*)&bet[lane*16+4];
  f32x4 b2 = *(const f32x4*)&bet[lane*16+8];
  f32x4 b3 = *(const f32x4*)&bet[lane*16+12];
  u16x8 o0, o1;
#pragma unroll
  for (int j=0;j<4;j++){
    o0[j]   = f2bf((x[j]   -mean)*rs*g0[j] + b0[j]);
    o0[4+j] = f2bf((x[4+j] -mean)*rs*g1[j] + b1[j]);
    o1[j]   = f2bf((x[8+j] -mean)*rs*g2[j] + b2[j]);
    o1[4+j] = f2bf((x[12+j]-mean)*rs*g3[j] + b3[j]);
  }
  *(u16x8*)&Y[(size_t)grow*NH + lane*16]     = o0;
  *(u16x8*)&Y[(size_t)grow*NH + lane*16 + 8] = o1;
}

// ---------------- ar / tar losses ----------------
__global__ __launch_bounds__(256)
void loss_partial(const unsigned short* __restrict__ Yu, float* __restrict__ partials)
{
  float ar = 0.f, tar = 0.f;
  long stride = (long)gridDim.x*256;
  for (long vv = (long)blockIdx.x*256 + threadIdx.x; vv < 2097152; vv += stride){
    long i = vv*8;
    int t = (int)((i >> 10) & 511);
    u16x8 y = *(const u16x8*)&Yu[i];
    float x[8];
#pragma unroll
    for (int q=0;q<8;q++){ x[q] = bf2f(y[q]); ar += x[q]*x[q]; }
    if (t > 0){
      u16x8 yp = *(const u16x8*)&Yu[i - 1024];
#pragma unroll
      for (int q=0;q<8;q++){ float d = x[q] - bf2f(yp[q]); tar += d*d; }
    }
  }
  ar += __shfl_xor(ar,1); ar += __shfl_xor(ar,2); ar += __shfl_xor(ar,4);
  ar += __shfl_xor(ar,8); ar += __shfl_xor(ar,16); ar += __shfl_xor(ar,32);
  tar += __shfl_xor(tar,1); tar += __shfl_xor(tar,2); tar += __shfl_xor(tar,4);
  tar += __shfl_xor(tar,8); tar += __shfl_xor(tar,16); tar += __shfl_xor(tar,32);
  __shared__ float red[16];
  int w = threadIdx.x >> 6;
  if ((threadIdx.x & 63) == 0){ red[w] = ar; red[8+w] = tar; }
  __syncthreads();
  if (threadIdx.x == 0){
    partials[blockIdx.x*2]   = red[0]+red[1]+red[2]+red[3];
    partials[blockIdx.x*2+1] = red[8]+red[9]+red[10]+red[11];
  }
}

__global__ __launch_bounds__(256)
void loss_final(const float* __restrict__ partials, float* __restrict__ oAr, float* __restrict__ oTar){
  double sa = 0.0, st = 0.0;
  for (int i = threadIdx.x; i < 1024; i += 256){ sa += (double)partials[2*i]; st += (double)partials[2*i+1]; }
  for (int m=1;m<64;m<<=1){ sa += __shfl_xor(sa, m); st += __shfl_xor(st, m); }
  __shared__ double rd[8];
  int w = threadIdx.x >> 6;
  if ((threadIdx.x & 63) == 0){ rd[w] = sa; rd[4+w] = st; }
  __syncthreads();
  if (threadIdx.x == 0){
    double a  = rd[0]+rd[1]+rd[2]+rd[3];
    double tt = rd[4]+rd[5]+rd[6]+rd[7];
    oAr[0]  = (float)(a  / 16777216.0 * 0.01);
    oTar[0] = (float)(tt / 16744448.0 * 0.01);
  }
}

// ---------------- launch ----------------
extern "C" void kernel_launch(void* const* d_in, const int* in_sizes, int n_in,
                              void* d_out, int out_size, void* d_ws, size_t ws_size,
                              hipStream_t stream)
{
  const float* obs  = (const float*)d_in[0];
  const float* hxs  = (const float*)d_in[1];
  const float* cxs  = (const float*)d_in[2];
  const float* W1   = (const float*)d_in[3];
  const float* b1   = (const float*)d_in[4];
  const float* W2   = (const float*)d_in[5];
  const float* b2   = (const float*)d_in[6];
  const float* W_ih = (const float*)d_in[7];
  const float* W_hh = (const float*)d_in[8];
  const float* b_ih = (const float*)d_in[9];
  const float* b_hh = (const float*)d_in[10];
  const float* ln_g = (const float*)d_in[11];
  const float* ln_b = (const float*)d_in[12];
  const float* Wa   = (const float*)d_in[13];
  const float* ba   = (const float*)d_in[14];
  const float* Wc   = (const float*)d_in[15];
  const float* bc   = (const float*)d_in[16];

  char* ws = (char*)d_ws;
  size_t off = 0;
  auto alloc = [&](size_t bytes)->char*{
    char* p = ws + off;
    off = (off + bytes + 255) & ~(size_t)255;
    return p;
  };
  // ---- fixed buffers (incl. full-size xg + hist) ----
  unsigned short* W1_b    = (unsigned short*)alloc((size_t)NE*ND*2);
  unsigned short* W2_b    = (unsigned short*)alloc((size_t)NE*NE*2);
  unsigned short* Wih_b   = (unsigned short*)alloc((size_t)4*NH*NE*2);
  unsigned short* Whead_b = (unsigned short*)alloc((size_t)128*NH*2);
  float* bias_heads       = (float*)alloc(65*4);
  float* bias_xg          = (float*)alloc(4096*4);
  unsigned short* outln_b = (unsigned short*)alloc((size_t)NB*NT*NH*2);   // 32 MB
  unsigned short* xg_f    = (unsigned short*)alloc((size_t)NB*NT*4096*2); // 128 MB, [b][t][4H]
  unsigned short* hist_f  = (unsigned short*)alloc((size_t)NB*NT*NH*2);   // 32 MB, [b][t][H]
  unsigned short* h16     = (unsigned short*)alloc((size_t)3*NB*NH*2);
  float* c_buf            = (float*)alloc((size_t)NB*NH*4);
  int*   flags            = (int*)alloc(8192*4);
  float* partials         = (float*)alloc((size_t)1024*2*4);
  const size_t fixedEnd = off;

  // GEMM chunk size: Tc=128 keeps per-chunk working sets cache-resident (r9/r11 evidence)
  int lg = -1;
  for (int L = 7; L >= 4; --L){
    size_t Mc = (size_t)NB << L;
    size_t per = Mc*ND*2 + 2*(Mc*NE*2) + 3*256;
    if (fixedEnd + per <= ws_size){ lg = L; break; }
  }
  if (lg < 0){ sentinel_kernel<<<1,1,0,stream>>>((float*)d_out); return; }
  const int Tc = 1 << lg;
  const int Mc = NB << lg;
  const int nChunks = NT >> lg;

  unsigned short* obs_c  = (unsigned short*)alloc((size_t)Mc*ND*2);
  unsigned short* enc1_c = (unsigned short*)alloc((size_t)Mc*NE*2);
  unsigned short* enc2_c = (unsigned short*)alloc((size_t)Mc*NE*2);

  float* o = (float*)d_out;
  float* oLogits = o;
  float* oValues = o + (size_t)NB*NT*64;
  float* oH  = oValues + NB*NT;
  float* oC  = oH + NB*NH;
  float* oAr = oC + NB*NH;
  float* oTar= oAr + 1;

  mega_prep<<<2048,256,0,stream>>>(W1, W2, W_ih, Wa, Wc, ba, bc, b_ih, b_hh, hxs, cxs,
                                   W1_b, W2_b, Wih_b, Whead_b, bias_heads, bias_xg,
                                   h16, c_buf, flags);

  // ---- GEMM complex: cache-resident chunks, xg written to full-T layout ----
  for (int c = 0; c < nChunks; ++c){
    int t0 = c << lg;
    f2b_obs_chunk<<<512,256,0,stream>>>(obs, obs_c, lg, t0);
    gemm_bt<1,0,0><<<dim3(Mc/128,8) ,256,0,stream>>>(obs_c,  W1_b,  b1,      enc1_c, nullptr, nullptr, ND, NE, NE, 0, 0);
    gemm_bt<1,0,0><<<dim3(Mc/128,8) ,256,0,stream>>>(enc1_c, W2_b,  b2,      enc2_c, nullptr, nullptr, NE, NE, NE, 0, 0);
    gemm_bt<0,0,1><<<dim3(Mc/128,32),256,0,stream>>>(enc2_c, Wih_b, bias_xg, xg_f,   nullptr, nullptr, NE, 4096, 4096, lg, t0);
  }

  // ---- single full-T LSTM dispatch ----
  lstm_mfma<<<256,512,LSTM_SMEM,stream>>>(xg_f, W_hh, h16, c_buf, hist_f, oH, oC, flags, 0, NT, NT);

  // ---- LN over all rows (identity row mapping at lgTc=9) ----
  ln_chunk<<<(NB*NT)/4,256,0,stream>>>(hist_f, ln_g, ln_b, outln_b, 9, 0);

  gemm_bt<0,1,0><<<dim3(128,1),256,0,stream>>>(outln_b, Whead_b, bias_heads, nullptr, oLogits, oValues, NH, 128, 65, 0, 0);
  loss_partial<<<1024,256,0,stream>>>(outln_b, partials);
  loss_final<<<1,256,0,stream>>>(partials, oAr, oTar);
}

// Round 13
// 2260.450 us; speedup vs baseline: 1.1183x; 1.1183x over previous
//
#include <hip/hip_runtime.h>

typedef __attribute__((ext_vector_type(8))) short bf16x8;
typedef __attribute__((ext_vector_type(8))) unsigned short u16x8;
typedef __attribute__((ext_vector_type(4))) unsigned short u16x4;
typedef __attribute__((ext_vector_type(4))) float f32x4;
typedef __attribute__((ext_vector_type(2))) unsigned int u32x2;

#define NB 32
#define NT 512
#define ND 256
#define NE 1024
#define NH 1024
#define LSTM_SMEM (131072 + 18432)   // W frags (hi+lo) + reduce buffer [16][32][9] f32

__device__ __forceinline__ float bf2f(unsigned short u){
  union { unsigned int i; float f; } w; w.i = ((unsigned int)u) << 16; return w.f;
}
__device__ __forceinline__ unsigned short f2bf(float f){
  union { float f; unsigned int i; } w; w.f = f;
  unsigned int r = (w.i >> 16) & 1u;
  return (unsigned short)((w.i + 0x7fffu + r) >> 16);
}

// ---- cache-bypass (coherence-point) memory ops ----
__device__ __forceinline__ bf16x8 bypass_load_b128(const unsigned short* p){
  bf16x8 r;
  asm volatile("global_load_dwordx4 %0, %1, off sc0 sc1" : "=v"(r) : "v"(p) : "memory");
  return r;  // caller must s_waitcnt before use
}
__device__ __forceinline__ int bypass_load_i32(const int* p){
  int r;
  asm volatile("global_load_dword %0, %1, off sc0 sc1\n\ts_waitcnt vmcnt(0)"
               : "=v"(r) : "v"(p) : "memory");
  return r;
}
__device__ __forceinline__ void bypass_store_b64(unsigned short* p, u32x2 v){
  asm volatile("global_store_dwordx2 %0, %1, off sc0 sc1" :: "v"(p), "v"(v) : "memory");
}
__device__ __forceinline__ void bypass_store_i32(int* p, int v){
  asm volatile("global_store_dword %0, %1, off sc0 sc1" :: "v"(p), "v"(v) : "memory");
}
__device__ __forceinline__ void bypass_store_u16(unsigned short* p, unsigned short v){
  asm volatile("global_store_short %0, %1, off sc0 sc1" :: "v"(p), "v"(v) : "memory");
}

// ---- global_load_lds width=16 (m97 pattern) ----
__device__ __forceinline__ void gload_lds16(const void* g, void* l){
  __builtin_amdgcn_global_load_lds(
      (const __attribute__((address_space(1))) void*)g,
      (__attribute__((address_space(3))) void*)l, 16, 0, 0);
}

// ---------------- one-shot prep: weight conversion + state init ----------------
__global__ void mega_prep(const float* __restrict__ W1, const float* __restrict__ W2,
                          const float* __restrict__ Wih,
                          const float* __restrict__ Wa, const float* __restrict__ Wc,
                          const float* __restrict__ ba, const float* __restrict__ bc,
                          const float* __restrict__ b_ih, const float* __restrict__ b_hh,
                          const float* __restrict__ hxs, const float* __restrict__ cxs,
                          unsigned short* __restrict__ W1_b, unsigned short* __restrict__ W2_b,
                          unsigned short* __restrict__ Wih_b, unsigned short* __restrict__ Whead_b,
                          float* __restrict__ bias_heads, float* __restrict__ bias_xg,
                          unsigned short* __restrict__ h16, float* __restrict__ c_buf,
                          int* __restrict__ flags)
{
  long i0 = (long)blockIdx.x*256 + threadIdx.x;
  long stride = (long)gridDim.x*256;
  for (long i=i0; i<(long)NE*ND;   i+=stride) W1_b[i]  = f2bf(W1[i]);
  for (long i=i0; i<(long)NE*NE;   i+=stride) W2_b[i]  = f2bf(W2[i]);
  for (long i=i0; i<(long)4*NH*NE; i+=stride) Wih_b[i] = f2bf(Wih[i]);
  for (long i=i0; i<128*1024; i+=stride){
    int n = (int)(i>>10), k = (int)(i&1023);
    Whead_b[i] = f2bf(n<64 ? Wa[i] : (n==64 ? Wc[k] : 0.f));
  }
  for (long i=i0; i<4096; i+=stride) bias_xg[i] = b_ih[i] + b_hh[i];
  for (long i=i0; i<65;   i+=stride) bias_heads[i] = (i<64) ? ba[i] : bc[0];
  for (long i=i0; i<NB*NH; i+=stride){ h16[i] = f2bf(hxs[i]); c_buf[i] = cxs[i]; }
  for (long i=i0; i<8192; i+=stride) flags[i] = 0;
}

__global__ void f2b_obs_chunk(const float* __restrict__ obs, unsigned short* __restrict__ dst,
                              int lgTc, int t0){
  const int Tc = 1 << lgTc;
  const long n = (long)NB * Tc * ND;
  long i = (long)blockIdx.x*blockDim.x + threadIdx.x;
  long stride = (long)gridDim.x*blockDim.x;
  for (; i < n; i += stride){
    long lr = i >> 8;
    int col = (int)(i & 255);
    long gr = (lr >> lgTc)*NT + t0 + (lr & (Tc-1));
    dst[i] = f2bf(obs[gr*ND + col]);
  }
}

__global__ void sentinel_kernel(float* __restrict__ out){ out[0] = 1.0e6f; }

// ---------------- bf16 MFMA GEMM: 128x128, dbuf LDS, 2-phase prefetch ----------------
// Rectangular XCD mapping: XCD x (= hw_id & 7) owns m-block stripe [x*gx/8, (x+1)*gx/8)
// for ALL n -> per-XCD A working set = 4MB (L2-resident), B panels stream.
// STREAMC=1: C stores via sc0sc1 bypass (no L2 allocation; preserves A-stripe).
#define GEMM_COMPUTE(P) { \
  bf16x8 af[4], bfr[4]; \
  _Pragma("unroll") for (int f=0; f<4; f++){ \
    af[f]  = *(const bf16x8*)&As[P][(wm*64 + f*16 + fr)*32 + kf]; \
    bfr[f] = *(const bf16x8*)&Bs[P][(wn*64 + f*16 + fr)*32 + kf]; } \
  _Pragma("unroll") for (int i=0;i<4;i++) \
    _Pragma("unroll") for (int j=0;j<4;j++) \
      acc[i][j] = __builtin_amdgcn_mfma_f32_16x16x32_bf16(af[i], bfr[j], acc[i][j], 0, 0, 0); }

template<int SILU, int HEADS, int STREAMC>
__global__ __launch_bounds__(256)
void gemm_bt(const unsigned short* __restrict__ A, const unsigned short* __restrict__ Bw,
             const float* __restrict__ bias, unsigned short* __restrict__ C,
             float* __restrict__ oLogits, float* __restrict__ oValues,
             int K, int N, int Nreal)
{
  __shared__ __align__(16) unsigned short As[2][128*32];
  __shared__ __align__(16) unsigned short Bs[2][128*32];
  const int tid = threadIdx.x;
  const int lane = tid & 63;
  const int w = tid >> 6;
  const int wm = w >> 1, wn = w & 1;
  // rectangular XCD-stripe mapping (hw round-robin: XCD = flat_id & 7)
  const int gx = gridDim.x;
  const int jf = blockIdx.y * gx + blockIdx.x;
  int m0, n0;
  if ((gx & 7) == 0){
    const int ms = gx >> 3;
    const int x = jf & 7, ii = jf >> 3;
    m0 = (x*ms + (ii % ms)) * 128;
    n0 = (ii / ms) * 128;
  } else {
    m0 = blockIdx.x * 128; n0 = blockIdx.y * 128;
  }
  f32x4 acc[4][4];
#pragma unroll
  for (int i=0;i<4;i++)
#pragma unroll
    for (int j=0;j<4;j++){ f32x4 z = {0.f,0.f,0.f,0.f}; acc[i][j] = z; }
  const int fr = lane & 15;
  const int kf = (lane >> 4) * 8;
  const int r0 = tid >> 2, s0 = tid & 3;
  const unsigned short* gA0 = A  + (size_t)(m0+r0)*K    + s0*8;
  const unsigned short* gA1 = A  + (size_t)(m0+r0+64)*K + s0*8;
  const unsigned short* gB0 = Bw + (size_t)(n0+r0)*K    + s0*8;
  const unsigned short* gB1 = Bw + (size_t)(n0+r0+64)*K + s0*8;

  auto stage = [&](int p, int k0){
    char* a = (char*)&As[p][0] + w*1024;
    char* b = (char*)&Bs[p][0] + w*1024;
    gload_lds16(gA0 + k0, a);
    gload_lds16(gA1 + k0, a + 4096);
    gload_lds16(gB0 + k0, b);
    gload_lds16(gB1 + k0, b + 4096);
  };

  stage(0, 0);
  asm volatile("s_waitcnt vmcnt(0)" ::: "memory");
  __syncthreads();
  int cur = 0;
  for (int k0 = 32; k0 < K; k0 += 32){
    stage(cur ^ 1, k0);
    GEMM_COMPUTE(cur);
    asm volatile("s_waitcnt vmcnt(0)" ::: "memory");
    __syncthreads();
    cur ^= 1;
  }
  GEMM_COMPUTE(cur);

  const int mb = (lane >> 4) * 4;
  const int nb = lane & 15;
#pragma unroll
  for (int i=0;i<4;i++)
#pragma unroll
    for (int j=0;j<4;j++)
#pragma unroll
      for (int r=0;r<4;r++){
        int m = m0 + wm*64 + i*16 + mb + r;
        int n = n0 + wn*64 + j*16 + nb;
        if (HEADS && n >= Nreal) continue;
        float v = acc[i][j][r] + bias[n];
        if (SILU) v = v / (1.f + expf(-v));
        if (!HEADS) {
          unsigned short cv = f2bf(v);
          if (STREAMC) bypass_store_u16(&C[(size_t)m*N + n], cv);
          else         C[(size_t)m*N + n] = cv;
        } else {
          if (n < 64) oLogits[(size_t)m*64 + n] = v;
          else if (n == 64) oValues[m] = v;
        }
      }
}

// ---------------- LSTM: persistent MFMA kernel (r10-verified, 977us), bf16-h exchange ----------------
__global__ __launch_bounds__(512)
void lstm_mfma(const unsigned short* __restrict__ xg, const float* __restrict__ Whh,
               unsigned short* __restrict__ h16, float* __restrict__ c_buf,
               unsigned short* __restrict__ hist, float* __restrict__ dh, float* __restrict__ dc,
               int* __restrict__ flags, int t0, int t1, int Tc)
{
  extern __shared__ char smem[];
  unsigned short* Wf = (unsigned short*)smem;          // [term][kt 32][nt 2][lane 64] x 8 ushort
  float* red = (float*)(smem + 131072);                // [batch 16][row 32][wv 9] (pad 9)
  const int wg = blockIdx.x;
  const int bh = wg & 1, ug = wg >> 1;
  const int b0 = bh*16, n0w = ug*8;
  const int tid = threadIdx.x;
  const int lane = tid & 63;
  const int wv = tid >> 6;
  const int fr = lane & 15;
  const int q8 = (lane >> 4) * 8;

  // ---- one-time: stage W hi/lo fragments ----
  for (int s = tid; s < 8192; s += 512){
    int term = s >> 12, kt = (s >> 7) & 31, nt = (s >> 6) & 1, l = s & 63;
    int r = nt*16 + (l & 15);
    int g = r >> 3, uu2 = r & 7;
    const float* src = Whh + (size_t)(g*NH + n0w + uu2)*NH + kt*32 + (l>>4)*8;
    u16x8 o;
#pragma unroll
    for (int j=0;j<8;j++){
      float wv_ = src[j];
      unsigned short hi = f2bf(wv_);
      o[j] = (term==0) ? hi : f2bf(wv_ - bf2f(hi));
    }
    *(u16x8*)&Wf[(size_t)s*8] = o;
  }

  const int bl = wv*2 + (lane >> 3);   // batch-local 0..15 (lane<16)
  const int uu = lane & 7;             // unit 0..7
  float c_reg = 0.f, h_keep = 0.f;
  if (lane < 16) c_reg = c_buf[(b0 + bl)*NH + n0w + uu];
  __syncthreads();

  int pcur = t0 % 3;                   // buffer holding state tag t0
  for (int t = t0; t < t1; t++){
    const int pnext = (pcur == 2) ? 0 : pcur + 1;
    const unsigned short* hb = h16 + (size_t)pcur  * (NB*NH);
    unsigned short* hb_next  = h16 + (size_t)pnext * (NB*NH);
    const int tl = t - t0;

    // xg prefetch (before poll; independent of h)
    float xgv[4] = {0.f,0.f,0.f,0.f};
    if (lane < 16){
      size_t xbase = ((size_t)(b0+bl)*Tc + tl)*4096 + n0w + uu;
#pragma unroll
      for (int g=0; g<4; g++) xgv[g] = bf2f(xg[xbase + g*1024]);
    }

    // ---- per-wave producer poll: wait my 16 producers finished step t-1 ----
    {
      const int pw = ((wv*16 + fr)*2 + bh) * 32;
      while (true){
        int v = bypass_load_i32(&flags[pw]);
        v = min(v, __shfl_xor(v, 1));
        v = min(v, __shfl_xor(v, 2));
        v = min(v, __shfl_xor(v, 4));
        v = min(v, __shfl_xor(v, 8));
        if (v >= t) break;
        __builtin_amdgcn_s_sleep(1);
      }
    }

    // ---- h A-frag loads: 4 x 16B, land directly as bf16 MFMA A-fragments ----
    bf16x8 a[4];
#pragma unroll
    for (int ks=0; ks<4; ks++)
      a[ks] = bypass_load_b128(hb + (size_t)(b0 + fr)*NH + (wv*4 + ks)*32 + q8);
    asm volatile("s_waitcnt vmcnt(0)" ::: "memory");
    __builtin_amdgcn_sched_barrier(0);

    f32x4 acc[2];
    { f32x4 z = {0.f,0.f,0.f,0.f}; acc[0] = z; acc[1] = z; }
#pragma unroll
    for (int ks=0; ks<4; ks++){
      int kt = wv*4 + ks;
#pragma unroll
      for (int nt=0; nt<2; nt++){
        bf16x8 bhi = *(const bf16x8*)&Wf[kt*1024 + nt*512 + lane*8];
        bf16x8 blo = *(const bf16x8*)&Wf[32768 + kt*1024 + nt*512 + lane*8];
        acc[nt] = __builtin_amdgcn_mfma_f32_16x16x32_bf16(a[ks], bhi, acc[nt], 0,0,0);
        acc[nt] = __builtin_amdgcn_mfma_f32_16x16x32_bf16(a[ks], blo, acc[nt], 0,0,0);
      }
    }

    // ---- cross-wave reduce: partials to LDS ([16][32][9] layout) ----
#pragma unroll
    for (int nt=0; nt<2; nt++)
#pragma unroll
      for (int r4=0; r4<4; r4++){
        int batch = (lane>>4)*4 + r4;
        red[batch*288 + (nt*16 + fr)*9 + wv] = acc[nt][r4];
      }
    __syncthreads();

    // ---- epilogue: lanes 0..15 of every wave, one (batch, unit) each ----
    unsigned short p0=0,p1=0,p2=0,p3=0;
    if (lane < 16){
      float gate[4];
#pragma unroll
      for (int g=0; g<4; g++){
        const float* rp = &red[bl*288 + (g*8 + uu)*9];
        float s = 0.f;
#pragma unroll
        for (int w8=0; w8<8; w8++) s += rp[w8];
        gate[g] = s + xgv[g];
      }
      float iv = 1.f/(1.f+expf(-gate[0]));
      float fv = 1.f/(1.f+expf(-gate[1]));
      float gv = tanhf(gate[2]);
      float ov = 1.f/(1.f+expf(-gate[3]));
      float c_new = fv*c_reg + iv*gv;
      float h_new = ov*tanhf(c_new);
      c_reg = c_new; h_keep = h_new;
      float h0 = __shfl(h_new, (lane & ~3) + 0);
      float h1 = __shfl(h_new, (lane & ~3) + 1);
      float h2 = __shfl(h_new, (lane & ~3) + 2);
      float h3 = __shfl(h_new, (lane & ~3) + 3);
      if ((lane & 3) == 0){
        p0 = f2bf(h0); p1 = f2bf(h1); p2 = f2bf(h2); p3 = f2bf(h3);
        u32x2 pk; pk[0] = (unsigned)p0 | ((unsigned)p1 << 16);
        pk[1] = (unsigned)p2 | ((unsigned)p3 << 16);
        bypass_store_b64(hb_next + (size_t)(b0+bl)*NH + n0w + uu, pk);
      }
    }
    // ---- publish: drain h stores, then single flag store ----
    asm volatile("s_waitcnt vmcnt(0)" ::: "memory");
    __syncthreads();
    if (tid == 0) bypass_store_i32(&flags[wg*32], t+1);
    // hist store AFTER publish (off the critical path)
    if (lane < 16 && (lane & 3) == 0){
      u16x4 hp = { p0, p1, p2, p3 };
      *(u16x4*)&hist[((size_t)(b0+bl)*Tc + tl)*NH + n0w + uu] = hp;
    }
    pcur = pnext;
  }
  if (lane < 16){
    c_buf[(b0+bl)*NH + n0w + uu] = c_reg;
    if (t1 == NT){ dh[(b0+bl)*NH + n0w + uu] = h_keep; dc[(b0+bl)*NH + n0w + uu] = c_reg; }
  }
}

// ---------------- LayerNorm: wave-per-row, 4 rows/block ----------------
__global__ __launch_bounds__(256)
void ln_chunk(const unsigned short* __restrict__ X, const float* __restrict__ gam, const float* __restrict__ bet,
              unsigned short* __restrict__ Y, int lgTc, int t0)
{
  const int Tc = 1 << lgTc;
  const int row = blockIdx.x*4 + (threadIdx.x >> 6);
  const int lane = threadIdx.x & 63;
  const int bl = row >> lgTc, tl = row & (Tc-1);
  const long grow = (long)bl*NT + t0 + tl;
  u16x8 a0 = *(const u16x8*)&X[(size_t)row*NH + lane*16];
  u16x8 a1 = *(const u16x8*)&X[(size_t)row*NH + lane*16 + 8];
  float x[16];
  float s = 0.f;
#pragma unroll
  for (int j=0;j<8;j++){ x[j] = bf2f(a0[j]); x[8+j] = bf2f(a1[j]); }
#pragma unroll
  for (int j=0;j<16;j++) s += x[j];
  s += __shfl_xor(s,1); s += __shfl_xor(s,2); s += __shfl_xor(s,4);
  s += __shfl_xor(s,8); s += __shfl_xor(s,16); s += __shfl_xor(s,32);
  const float mean = s * (1.0f/NH);
  float q = 0.f;
#pragma unroll
  for (int j=0;j<16;j++){ float d = x[j]-mean; q += d*d; }
  q += __shfl_xor(q,1); q += __shfl_xor(q,2); q += __shfl_xor(q,4);
  q += __shfl_xor(q,8); q += __shfl_xor(q,16); q += __shfl_xor(q,32);
  const float rs = 1.f / sqrtf(q * (1.0f/NH) + 1e-5f);
  f32x4 g0 = *(const f32x4*)&gam[lane*16];
  f32x4 g1 = *(const f32x4*)&gam[lane*16+4];
  f32x4 g2 = *(const f32x4*)&gam[lane*16+8];
  f32x4 g3 = *(const f32x4*)&gam[lane*16+12];
  f32x4 b0 = *(const f32x4*)&bet[lane*16];
  f32x4 b1 = *(const f32x4*)&bet[lane*16+4];
  f32x4 b2 = *(const f32x4*)&bet[lane*16+8];
  f32x4 b3 = *(const f32x4*)&bet[lane*16+12];
  u16x8 o0, o1;
#pragma unroll
  for (int j=0;j<4;j++){
    o0[j]   = f2bf((x[j]   -mean)*rs*g0[j] + b0[j]);
    o0[4+j] = f2bf((x[4+j] -mean)*rs*g1[j] + b1[j]);
    o1[j]   = f2bf((x[8+j] -mean)*rs*g2[j] + b2[j]);
    o1[4+j] = f2bf((x[12+j]-mean)*rs*g3[j] + b3[j]);
  }
  *(u16x8*)&Y[(size_t)grow*NH + lane*16]     = o0;
  *(u16x8*)&Y[(size_t)grow*NH + lane*16 + 8] = o1;
}

// ---------------- ar / tar losses ----------------
__global__ __launch_bounds__(256)
void loss_partial(const unsigned short* __restrict__ Yu, float* __restrict__ partials)
{
  float ar = 0.f, tar = 0.f;
  long stride = (long)gridDim.x*256;
  for (long vv = (long)blockIdx.x*256 + threadIdx.x; vv < 2097152; vv += stride){
    long i = vv*8;
    int t = (int)((i >> 10) & 511);
    u16x8 y = *(const u16x8*)&Yu[i];
    float x[8];
#pragma unroll
    for (int q=0;q<8;q++){ x[q] = bf2f(y[q]); ar += x[q]*x[q]; }
    if (t > 0){
      u16x8 yp = *(const u16x8*)&Yu[i - 1024];
#pragma unroll
      for (int q=0;q<8;q++){ float d = x[q] - bf2f(yp[q]); tar += d*d; }
    }
  }
  ar += __shfl_xor(ar,1); ar += __shfl_xor(ar,2); ar += __shfl_xor(ar,4);
  ar += __shfl_xor(ar,8); ar += __shfl_xor(ar,16); ar += __shfl_xor(ar,32);
  tar += __shfl_xor(tar,1); tar += __shfl_xor(tar,2); tar += __shfl_xor(tar,4);
  tar += __shfl_xor(tar,8); tar += __shfl_xor(tar,16); tar += __shfl_xor(tar,32);
  __shared__ float red[16];
  int w = threadIdx.x >> 6;
  if ((threadIdx.x & 63) == 0){ red[w] = ar; red[8+w] = tar; }
  __syncthreads();
  if (threadIdx.x == 0){
    partials[blockIdx.x*2]   = red[0]+red[1]+red[2]+red[3];
    partials[blockIdx.x*2+1] = red[8]+red[9]+red[10]+red[11];
  }
}

__global__ __launch_bounds__(256)
void loss_final(const float* __restrict__ partials, float* __restrict__ oAr, float* __restrict__ oTar){
  double sa = 0.0, st = 0.0;
  for (int i = threadIdx.x; i < 1024; i += 256){ sa += (double)partials[2*i]; st += (double)partials[2*i+1]; }
  for (int m=1;m<64;m<<=1){ sa += __shfl_xor(sa, m); st += __shfl_xor(st, m); }
  __shared__ double rd[8];
  int w = threadIdx.x >> 6;
  if ((threadIdx.x & 63) == 0){ rd[w] = sa; rd[4+w] = st; }
  __syncthreads();
  if (threadIdx.x == 0){
    double a  = rd[0]+rd[1]+rd[2]+rd[3];
    double tt = rd[4]+rd[5]+rd[6]+rd[7];
    oAr[0]  = (float)(a  / 16777216.0 * 0.01);
    oTar[0] = (float)(tt / 16744448.0 * 0.01);
  }
}

// ---------------- launch ----------------
extern "C" void kernel_launch(void* const* d_in, const int* in_sizes, int n_in,
                              void* d_out, int out_size, void* d_ws, size_t ws_size,
                              hipStream_t stream)
{
  const float* obs  = (const float*)d_in[0];
  const float* hxs  = (const float*)d_in[1];
  const float* cxs  = (const float*)d_in[2];
  const float* W1   = (const float*)d_in[3];
  const float* b1   = (const float*)d_in[4];
  const float* W2   = (const float*)d_in[5];
  const float* b2   = (const float*)d_in[6];
  const float* W_ih = (const float*)d_in[7];
  const float* W_hh = (const float*)d_in[8];
  const float* b_ih = (const float*)d_in[9];
  const float* b_hh = (const float*)d_in[10];
  const float* ln_g = (const float*)d_in[11];
  const float* ln_b = (const float*)d_in[12];
  const float* Wa   = (const float*)d_in[13];
  const float* ba   = (const float*)d_in[14];
  const float* Wc   = (const float*)d_in[15];
  const float* bc   = (const float*)d_in[16];

  char* ws = (char*)d_ws;
  size_t off = 0;
  auto alloc = [&](size_t bytes)->char*{
    char* p = ws + off;
    off = (off + bytes + 255) & ~(size_t)255;
    return p;
  };
  unsigned short* W1_b    = (unsigned short*)alloc((size_t)NE*ND*2);
  unsigned short* W2_b    = (unsigned short*)alloc((size_t)NE*NE*2);
  unsigned short* Wih_b   = (unsigned short*)alloc((size_t)4*NH*NE*2);
  unsigned short* Whead_b = (unsigned short*)alloc((size_t)128*NH*2);
  float* bias_heads       = (float*)alloc(65*4);
  float* bias_xg          = (float*)alloc(4096*4);
  unsigned short* outln_b = (unsigned short*)alloc((size_t)NB*NT*NH*2);   // 32 MB
  unsigned short* h16     = (unsigned short*)alloc((size_t)3*NB*NH*2);    // 3-buffer rotation
  float* c_buf            = (float*)alloc((size_t)NB*NH*4);
  int*   flags            = (int*)alloc(8192*4);
  float* partials         = (float*)alloc((size_t)1024*2*4);
  const size_t fixedEnd = off;

  // largest chunk that fits (Tc=512 -> monolithic: single lstm dispatch, xg L3-warm)
  int lg = -1;
  for (int L = 9; L >= 4; --L){
    size_t Mc = (size_t)NB << L;
    size_t per = Mc*ND*2 + 2*(Mc*NE*2) + Mc*4096*2 + Mc*NH*2 + 6*256;
    if (fixedEnd + per <= ws_size){ lg = L; break; }
  }
  if (lg < 0){ sentinel_kernel<<<1,1,0,stream>>>((float*)d_out); return; }
  const int Tc = 1 << lg;
  const int Mc = NB << lg;
  const int nChunks = NT >> lg;

  unsigned short* obs_c  = (unsigned short*)alloc((size_t)Mc*ND*2);
  unsigned short* enc1_c = (unsigned short*)alloc((size_t)Mc*NE*2);
  unsigned short* enc2_c = (unsigned short*)alloc((size_t)Mc*NE*2);
  unsigned short* xg_c   = (unsigned short*)alloc((size_t)Mc*4096*2);
  unsigned short* hist_c = (unsigned short*)alloc((size_t)Mc*NH*2);

  float* o = (float*)d_out;
  float* oLogits = o;
  float* oValues = o + (size_t)NB*NT*64;
  float* oH  = oValues + NB*NT;
  float* oC  = oH + NB*NH;
  float* oAr = oC + NB*NH;
  float* oTar= oAr + 1;

  mega_prep<<<2048,256,0,stream>>>(W1, W2, W_ih, Wa, Wc, ba, bc, b_ih, b_hh, hxs, cxs,
                                   W1_b, W2_b, Wih_b, Whead_b, bias_heads, bias_xg,
                                   h16, c_buf, flags);

  for (int c = 0; c < nChunks; ++c){
    int t0 = c << lg, t1 = t0 + Tc;
    f2b_obs_chunk<<<512,256,0,stream>>>(obs, obs_c, lg, t0);
    gemm_bt<1,0,0><<<dim3(Mc/128,8) ,256,0,stream>>>(obs_c,  W1_b,  b1,      enc1_c, nullptr, nullptr, ND, NE, NE);
    gemm_bt<1,0,0><<<dim3(Mc/128,8) ,256,0,stream>>>(enc1_c, W2_b,  b2,      enc2_c, nullptr, nullptr, NE, NE, NE);
    gemm_bt<0,0,1><<<dim3(Mc/128,32),256,0,stream>>>(enc2_c, Wih_b, bias_xg, xg_c,   nullptr, nullptr, NE, 4096, 4096);

    lstm_mfma<<<256,512,LSTM_SMEM,stream>>>(xg_c, W_hh, h16, c_buf, hist_c, oH, oC, flags, t0, t1, Tc);

    ln_chunk<<<Mc/4,256,0,stream>>>(hist_c, ln_g, ln_b, outln_b, lg, t0);
  }

  gemm_bt<0,1,0><<<dim3(128,1),256,0,stream>>>(outln_b, Whead_b, bias_heads, nullptr, oLogits, oValues, NH, 128, 65);
  loss_partial<<<1024,256,0,stream>>>(outln_b, partials);
  loss_final<<<1,256,0,stream>>>(partials, oAr, oTar);
}